// Round 5
// baseline (545.235 us; speedup 1.0000x reference)
//
#include <hip/hip_runtime.h>
#include <hip/hip_fp16.h>
#include <cstdint>

#define NNODES 50000

__device__ inline void wave_lds_fence() {
  asm volatile("s_waitcnt lgkmcnt(0)" ::: "memory");
  __builtin_amdgcn_wave_barrier();
}

// ---------------- CSR build ----------------
__global__ void hist_kernel(const int* __restrict__ ei, int E, int Nn, int* __restrict__ cnt) {
  int i = blockIdx.x * blockDim.x + threadIdx.x;
  int ET = E + Nn;
  if (i >= ET) return;
  int d = (i < E) ? ei[E + i] : (i - E);
  atomicAdd(&cnt[d], 1);
}

__global__ void scan1_kernel(const int* __restrict__ in, int n, int* __restrict__ incl,
                             int* __restrict__ bsum) {
  __shared__ int sd[256];
  int g = blockIdx.x * 256 + threadIdx.x;
  int v = (g < n) ? in[g] : 0;
  sd[threadIdx.x] = v;
  __syncthreads();
  for (int off = 1; off < 256; off <<= 1) {
    int t = (threadIdx.x >= off) ? sd[threadIdx.x - off] : 0;
    __syncthreads();
    sd[threadIdx.x] += t;
    __syncthreads();
  }
  if (g < n) incl[g] = sd[threadIdx.x];
  if (threadIdx.x == 255) bsum[blockIdx.x] = sd[255];
}

__global__ void scan3_kernel(const int* __restrict__ incl, const int* __restrict__ bscan,
                             int n, int* __restrict__ rowptr) {
  int g = blockIdx.x * 256 + threadIdx.x;
  if (g == 0) rowptr[0] = 0;
  if (g < n) {
    int off = (blockIdx.x > 0) ? bscan[blockIdx.x - 1] : 0;
    rowptr[g + 1] = incl[g] + off;
  }
}

__global__ void scatter_kernel(const int* __restrict__ ei, int E, int Nn,
                               const int* __restrict__ rowptr, int* __restrict__ cnt2,
                               int* __restrict__ esorted) {
  int i = blockIdx.x * blockDim.x + threadIdx.x;
  int ET = E + Nn;
  if (i >= ET) return;
  int s, d;
  if (i < E) { s = ei[i]; d = ei[E + i]; }
  else       { s = i - E; d = i - E; }
  int pos = rowptr[d] + atomicAdd(&cnt2[d], 1);
  esorted[pos] = s;
}

// ---------------- GEMM: Hout[N,HC](fp16) = X[N,FIN] @ W[FIN,HC](fp32) ----------------
template <int FIN, int HC, int BLOCK, typename XT>
__global__ __launch_bounds__(BLOCK) void gemm_kernel(const XT* __restrict__ X,
                                                     const float* __restrict__ W,
                                                     __half* __restrict__ Hout) {
  constexpr int NT = 16;
  constexpr int TM = 4, TN = 4;
  constexpr int CG = HC / TN;
  __shared__ __align__(16) float xs[FIN * NT];  // [k][node]
  const int n0 = blockIdx.x * NT;
  if constexpr (sizeof(XT) == 4) {
    for (int i = threadIdx.x * 4; i < NT * FIN; i += BLOCK * 4) {
      float4 v = *(const float4*)((const float*)X + (size_t)n0 * FIN + i);
      int node = i / FIN, k = i % FIN;
      xs[(k + 0) * NT + node] = v.x;
      xs[(k + 1) * NT + node] = v.y;
      xs[(k + 2) * NT + node] = v.z;
      xs[(k + 3) * NT + node] = v.w;
    }
  } else {
    for (int i = threadIdx.x * 8; i < NT * FIN; i += BLOCK * 8) {
      union { uint4 u; __half2 h2[4]; } raw;
      raw.u = *(const uint4*)((const __half*)X + (size_t)n0 * FIN + i);
      int node = i / FIN, k = i % FIN;  // FIN%8==0 -> same node
#pragma unroll
      for (int j = 0; j < 4; ++j) {
        float2 f = __half22float2(raw.h2[j]);
        xs[(k + 2 * j + 0) * NT + node] = f.x;
        xs[(k + 2 * j + 1) * NT + node] = f.y;
      }
    }
  }
  __syncthreads();
  const int cg = threadIdx.x % CG;
  const int ng = threadIdx.x / CG;
  if (ng >= NT / TM) return;
  const int c0 = cg * TN;
  const int i0 = ng * TM;
  float acc[TM][TN];
#pragma unroll
  for (int i = 0; i < TM; ++i)
#pragma unroll
    for (int j = 0; j < TN; ++j) acc[i][j] = 0.f;
#pragma unroll 4
  for (int k = 0; k < FIN; ++k) {
    const float4 wv = *(const float4*)(W + (size_t)k * HC + c0);
    const float4 xv = *(const float4*)(xs + k * NT + i0);
    acc[0][0] += xv.x * wv.x; acc[0][1] += xv.x * wv.y; acc[0][2] += xv.x * wv.z; acc[0][3] += xv.x * wv.w;
    acc[1][0] += xv.y * wv.x; acc[1][1] += xv.y * wv.y; acc[1][2] += xv.y * wv.z; acc[1][3] += xv.y * wv.w;
    acc[2][0] += xv.z * wv.x; acc[2][1] += xv.z * wv.y; acc[2][2] += xv.z * wv.z; acc[2][3] += xv.z * wv.w;
    acc[3][0] += xv.w * wv.x; acc[3][1] += xv.w * wv.y; acc[3][2] += xv.w * wv.z; acc[3][3] += xv.w * wv.w;
  }
#pragma unroll
  for (int i = 0; i < TM; ++i) {
    union { __half2 h2[2]; uint2 u; } pk;
    pk.h2[0] = __floats2half2_rn(acc[i][0], acc[i][1]);
    pk.h2[1] = __floats2half2_rn(acc[i][2], acc[i][3]);
    *(uint2*)(Hout + (size_t)(n0 + i0 + i) * HC + c0) = pk.u;
  }
}

// ---------------- attention logits (reads fp16 h, writes stride-8 padded) ----------------
template <int H, int C>
__global__ void alpha_kernel(const __half* __restrict__ Hbuf, const float* __restrict__ a_s,
                             const float* __restrict__ a_d, float* __restrict__ als8,
                             float* __restrict__ ald8, int n_nodes) {
  int i = blockIdx.x * blockDim.x + threadIdx.x;
  if (i >= n_nodes * H) return;
  int n = i / H, h = i % H;
  const __half2* hp = (const __half2*)(Hbuf + (size_t)n * H * C + (size_t)h * C);
  float s1 = 0.f, s2 = 0.f;
#pragma unroll
  for (int c = 0; c < C / 2; ++c) {
    float2 f = __half22float2(hp[c]);
    s1 += f.x * a_s[h * C + 2 * c] + f.y * a_s[h * C + 2 * c + 1];
    s2 += f.x * a_d[h * C + 2 * c] + f.y * a_d[h * C + 2 * c + 1];
  }
  als8[n * 8 + h] = s1;
  ald8[n * 8 + h] = s2;
}

// ---------------- segment softmax + aggregate, layers 1-2 (one wave per dst) ----------------
// No max-subtraction: scores are O(+-5); exp() safe in fp32, result identical.
template <int H, int C, int RELU>
__global__ __launch_bounds__(256, 8) void agg_kernel(const __half* __restrict__ Hbuf,
                                                     const float* __restrict__ als8,
                                                     const float* __restrict__ ald8,
                                                     const int* __restrict__ rowptr,
                                                     const int* __restrict__ esrc,
                                                     const float* __restrict__ bias,
                                                     __half* __restrict__ Out, int n_nodes) {
  constexpr int HC = H * C;
  constexpr int PAIRS = HC / 2;  // <= 64
  constexpr int CP2 = C / 2;
  constexpr int UN = 8;          // edge-sweep unroll (MLP)
  constexpr int SW = H | 1;      // odd stride -> conflict-free LDS writes
  const int wave = threadIdx.x >> 6;
  const int lane = threadIdx.x & 63;
  const int n = blockIdx.x * 4 + wave;
  __shared__ float s_w[4][64 * SW];
  __shared__ int s_src[4][64];
  if (n >= n_nodes) return;

  const int e0 = rowptr[n];
  const int e1 = rowptr[n + 1];

  float aldn[H];
#pragma unroll
  for (int h = 0; h < H; ++h) aldn[h] = ald8[n * 8 + h];

  const int pj = lane;
  const int hd = pj / CP2;

  float acc0 = 0.f, acc1 = 0.f;
  float ls[H];
#pragma unroll
  for (int h = 0; h < H; ++h) ls[h] = 0.f;

  for (int base = e0; base < e1; base += 64) {
    const int cnt = (e1 - base < 64) ? (e1 - base) : 64;
    int sreg = 0;
    if (lane < cnt) sreg = esrc[base + lane];
    s_src[wave][lane] = sreg;
    if (lane < cnt) {
      const float4 qa = *(const float4*)(als8 + (size_t)sreg * 8);
      const float4 qb = *(const float4*)(als8 + (size_t)sreg * 8 + 4);
      const float q[8] = {qa.x, qa.y, qa.z, qa.w, qb.x, qb.y, qb.z, qb.w};
#pragma unroll
      for (int h = 0; h < H; ++h) {
        float v = q[h] + aldn[h];
        v = v > 0.f ? v : 0.2f * v;  // leaky_relu 0.2
        float w = __expf(v);
        ls[h] += w;
        s_w[wave][lane * SW + h] = w;
      }
    } else {
#pragma unroll
      for (int h = 0; h < H; ++h) s_w[wave][lane * SW + h] = 0.f;
    }
    wave_lds_fence();
    if (pj < PAIRS) {
      for (int t = 0; t < cnt; t += UN) {
        int so[UN];
#pragma unroll
        for (int k = 0; k < UN; ++k) so[k] = s_src[wave][t + k] * HC;
        __half2 f[UN];
#pragma unroll
        for (int k = 0; k < UN; ++k) f[k] = *(const __half2*)(Hbuf + so[k] + 2 * pj);
#pragma unroll
        for (int k = 0; k < UN; ++k) {
          float w = s_w[wave][(t + k) * SW + hd];
          float2 ff = __half22float2(f[k]);
          acc0 += w * ff.x;
          acc1 += w * ff.y;
        }
      }
    }
    wave_lds_fence();
  }
  // reduce per-head weight sums across the wave (each lane held its own edges' w)
#pragma unroll
  for (int h = 0; h < H; ++h) {
    float v = ls[h];
#pragma unroll
    for (int off = 32; off > 0; off >>= 1) v += __shfl_xor(v, off, 64);
    ls[h] = v;
  }
  if (pj < PAIRS) {
    float inv = 1.f / ls[hd];
    float2 bv = *(const float2*)(bias + 2 * pj);
    float o0 = acc0 * inv + bv.x;
    float o1 = acc1 * inv + bv.y;
    if (RELU) { o0 = fmaxf(o0, 0.f); o1 = fmaxf(o1, 0.f); }
    *(__half2*)(Out + (size_t)n * HC + 2 * pj) = __floats2half2_rn(o0, o1);
  }
}

// ---------------- layer-3 prep: ws3h[h][k] = sum_c W3[k, h*40+c]*a_src3[h,c] ----------------
__global__ void prep3_kernel(const float* __restrict__ W3, const float* __restrict__ as3,
                             const float* __restrict__ ad3, float* __restrict__ ws3h,
                             float* __restrict__ wd3h) {
  int h = blockIdx.x, k = threadIdx.x;  // 6 x 96
  float s1 = 0.f, s2 = 0.f;
  for (int c = 0; c < 40; ++c) {
    float w = W3[k * 240 + h * 40 + c];
    s1 += w * as3[h * 40 + c];
    s2 += w * ad3[h * 40 + c];
  }
  ws3h[h * 96 + k] = s1;
  wd3h[h * 96 + k] = s2;
}

// ---------------- layer-3 logits from x2 directly ----------------
__global__ void alpha3_kernel(const __half* __restrict__ X2h, const float* __restrict__ ws3h,
                              const float* __restrict__ wd3h, float* __restrict__ als8,
                              float* __restrict__ ald8, int n_nodes) {
  int i = blockIdx.x * blockDim.x + threadIdx.x;
  if (i >= n_nodes * 6) return;
  int n = i / 6, h = i % 6;
  const __half2* xp = (const __half2*)(X2h + (size_t)n * 96);
  const float* sp = ws3h + h * 96;
  const float* dp = wd3h + h * 96;
  float s1 = 0.f, s2 = 0.f;
#pragma unroll
  for (int c = 0; c < 48; ++c) {
    float2 f = __half22float2(xp[c]);
    s1 += f.x * sp[2 * c] + f.y * sp[2 * c + 1];
    s2 += f.x * dp[2 * c] + f.y * dp[2 * c + 1];
  }
  als8[n * 8 + h] = s1;
  ald8[n * 8 + h] = s2;
}

// ---------------- layer-3 aggregation in x2-space: g[n,h,:] = sum_e alpha_eh * x2[src_e] ----------------
__global__ __launch_bounds__(256, 8) void agg3x_kernel(const __half* __restrict__ X2h,
                                                       const float* __restrict__ als8,
                                                       const float* __restrict__ ald8,
                                                       const int* __restrict__ rowptr,
                                                       const int* __restrict__ esrc,
                                                       __half* __restrict__ G, int n_nodes) {
  constexpr int H = 6, CIN = 96, P = 48, UN = 8;
  constexpr int SW = 9;  // odd stride -> conflict-free LDS writes
  const int wave = threadIdx.x >> 6;
  const int lane = threadIdx.x & 63;
  const int n = blockIdx.x * 4 + wave;
  __shared__ float s_w[4][64 * SW];
  __shared__ int s_src[4][64];
  if (n >= n_nodes) return;

  const int e0 = rowptr[n];
  const int e1 = rowptr[n + 1];

  float aldn[H];
#pragma unroll
  for (int h = 0; h < H; ++h) aldn[h] = ald8[n * 8 + h];

  float acc0[H], acc1[H], ls[H];
#pragma unroll
  for (int h = 0; h < H; ++h) { acc0[h] = 0.f; acc1[h] = 0.f; ls[h] = 0.f; }

  for (int base = e0; base < e1; base += 64) {
    const int cnt = (e1 - base < 64) ? (e1 - base) : 64;
    int sreg = 0;
    if (lane < cnt) sreg = esrc[base + lane];
    s_src[wave][lane] = sreg;
    if (lane < cnt) {
      const float4 qa = *(const float4*)(als8 + (size_t)sreg * 8);
      const float2 qb = *(const float2*)(als8 + (size_t)sreg * 8 + 4);
      const float q[6] = {qa.x, qa.y, qa.z, qa.w, qb.x, qb.y};
#pragma unroll
      for (int h = 0; h < H; ++h) {
        float v = q[h] + aldn[h];
        v = v > 0.f ? v : 0.2f * v;
        float w = __expf(v);
        ls[h] += w;
        s_w[wave][lane * SW + h] = w;
      }
    } else {
#pragma unroll
      for (int h = 0; h < H; ++h) s_w[wave][lane * SW + h] = 0.f;
    }
    wave_lds_fence();
    if (lane < P) {
      for (int t = 0; t < cnt; t += UN) {
        int so[UN];
#pragma unroll
        for (int k = 0; k < UN; ++k) so[k] = s_src[wave][t + k] * CIN;
        __half2 f[UN];
#pragma unroll
        for (int k = 0; k < UN; ++k) f[k] = *(const __half2*)(X2h + so[k] + 2 * lane);
#pragma unroll
        for (int k = 0; k < UN; ++k) {
          const float* wp = &s_w[wave][(t + k) * SW];
          float2 ff = __half22float2(f[k]);
#pragma unroll
          for (int h = 0; h < H; ++h) {
            float w = wp[h];  // scalar LDS broadcast
            acc0[h] += w * ff.x;
            acc1[h] += w * ff.y;
          }
        }
      }
    }
    wave_lds_fence();
  }
#pragma unroll
  for (int h = 0; h < H; ++h) {
    float v = ls[h];
#pragma unroll
    for (int off = 32; off > 0; off >>= 1) v += __shfl_xor(v, off, 64);
    ls[h] = 1.f / v;
  }
  if (lane < P) {
#pragma unroll
    for (int h = 0; h < H; ++h) {
      *(__half2*)(G + (size_t)n * 576 + h * 96 + 2 * lane) =
          __floats2half2_rn(acc0[h] * ls[h], acc1[h] * ls[h]);
    }
  }
}

// ---------------- layer-3 per-head GEMM: out[:, h*40:+40] = g[:,h,:] @ W3[:, h*40:+40] + b ----------------
__global__ __launch_bounds__(64) void gemm3h_kernel(const __half* __restrict__ G,
                                                    const float* __restrict__ W3,
                                                    const float* __restrict__ b3,
                                                    float* __restrict__ Out) {
  constexpr int NT = 16, TM = 4, TN = 4, CG = 10;
  const int h = blockIdx.y;
  __shared__ __align__(16) float xs[96 * NT];
  const int n0 = blockIdx.x * NT;
  for (int i = threadIdx.x * 8; i < NT * 96; i += 64 * 8) {
    int node = i / 96, k = i % 96;  // 96%8==0
    union { uint4 u; __half2 h2[4]; } raw;
    raw.u = *(const uint4*)(G + (size_t)(n0 + node) * 576 + h * 96 + k);
#pragma unroll
    for (int j = 0; j < 4; ++j) {
      float2 f = __half22float2(raw.h2[j]);
      xs[(k + 2 * j + 0) * NT + node] = f.x;
      xs[(k + 2 * j + 1) * NT + node] = f.y;
    }
  }
  __syncthreads();
  const int cg = threadIdx.x % CG;
  const int ng = threadIdx.x / CG;
  if (ng >= NT / TM) return;
  const int c0 = cg * TN;
  const int i0 = ng * TM;
  float acc[TM][TN];
#pragma unroll
  for (int i = 0; i < TM; ++i)
#pragma unroll
    for (int j = 0; j < TN; ++j) acc[i][j] = 0.f;
#pragma unroll 4
  for (int k = 0; k < 96; ++k) {
    const float4 wv = *(const float4*)(W3 + (size_t)k * 240 + h * 40 + c0);
    const float4 xv = *(const float4*)(xs + k * NT + i0);
    acc[0][0] += xv.x * wv.x; acc[0][1] += xv.x * wv.y; acc[0][2] += xv.x * wv.z; acc[0][3] += xv.x * wv.w;
    acc[1][0] += xv.y * wv.x; acc[1][1] += xv.y * wv.y; acc[1][2] += xv.y * wv.z; acc[1][3] += xv.y * wv.w;
    acc[2][0] += xv.z * wv.x; acc[2][1] += xv.z * wv.y; acc[2][2] += xv.z * wv.z; acc[2][3] += xv.z * wv.w;
    acc[3][0] += xv.w * wv.x; acc[3][1] += xv.w * wv.y; acc[3][2] += xv.w * wv.z; acc[3][3] += xv.w * wv.w;
  }
  const float4 bv = *(const float4*)(b3 + h * 40 + c0);
#pragma unroll
  for (int i = 0; i < TM; ++i) {
    float4 o;
    o.x = acc[i][0] + bv.x; o.y = acc[i][1] + bv.y;
    o.z = acc[i][2] + bv.z; o.w = acc[i][3] + bv.w;
    *(float4*)(Out + (size_t)(n0 + i0 + i) * 240 + h * 40 + c0) = o;
  }
}

// ---------------- launch ----------------
extern "C" void kernel_launch(void* const* d_in, const int* in_sizes, int n_in,
                              void* d_out, int out_size, void* d_ws, size_t ws_size,
                              hipStream_t stream) {
  const int N = NNODES;
  const float* x  = (const float*)d_in[0];
  const int* ei   = (const int*)d_in[1];
  const float* W1 = (const float*)d_in[2];
  const float* as1 = (const float*)d_in[3];
  const float* ad1 = (const float*)d_in[4];
  const float* b1  = (const float*)d_in[5];
  const float* W2  = (const float*)d_in[6];
  const float* as2 = (const float*)d_in[7];
  const float* ad2 = (const float*)d_in[8];
  const float* b2  = (const float*)d_in[9];
  const float* W3  = (const float*)d_in[10];
  const float* as3 = (const float*)d_in[11];
  const float* ad3 = (const float*)d_in[12];
  const float* b3  = (const float*)d_in[13];
  float* out = (float*)d_out;
  const int E = in_sizes[1] / 2;
  const int ET = E + N;

  char* ws = (char*)d_ws;
  size_t off = 0;
  auto alloc = [&](size_t bytes) -> char* {
    char* p = ws + off;
    off += (bytes + 255) & ~(size_t)255;
    return p;
  };
  int* cnt     = (int*)alloc((size_t)N * 4);
  int* cnt2    = (int*)alloc((size_t)N * 4);
  int* incl    = (int*)alloc((size_t)N * 4);
  int* bsum    = (int*)alloc(512 * 4);
  int* bscan   = (int*)alloc(256 * 4);
  int* rowptr  = (int*)alloc((size_t)(N + 1) * 4);
  int* esorted = (int*)alloc((size_t)ET * 4);
  float* als   = (float*)alloc((size_t)N * 8 * 4);
  float* ald   = (float*)alloc((size_t)N * 8 * 4);
  float* ws3h  = (float*)alloc(6 * 96 * 4);
  float* wd3h  = (float*)alloc(6 * 96 * 4);
  __half* x2h  = (__half*)alloc((size_t)N * 96 * 2);
  // g-region (57.6 MB); x1h and hbuf alias its front (dead before agg3x writes g)
  __half* g    = (__half*)alloc((size_t)N * 576 * 2);
  __half* x1h  = g;                                   // N*112*2 = 11.2 MB
  __half* hbuf = g + (size_t)N * 112;                 // N*112*2 = 11.2 MB (h1 112ch / h2 96ch)

  hipMemsetAsync(cnt, 0, (size_t)N * 4, stream);
  hipMemsetAsync(cnt2, 0, (size_t)N * 4, stream);

  const int B1 = (N + 255) / 256;
  hist_kernel<<<(ET + 255) / 256, 256, 0, stream>>>(ei, E, N, cnt);
  scan1_kernel<<<B1, 256, 0, stream>>>(cnt, N, incl, bsum);
  scan1_kernel<<<1, 256, 0, stream>>>(bsum, B1, bscan, bsum + 256);
  scan3_kernel<<<B1, 256, 0, stream>>>(incl, bscan, N, rowptr);
  scatter_kernel<<<(ET + 255) / 256, 256, 0, stream>>>(ei, E, N, rowptr, cnt2, esorted);
  prep3_kernel<<<6, 96, 0, stream>>>(W3, as3, ad3, ws3h, wd3h);

  // Layer 1: 128 -> 7x16
  gemm_kernel<128, 112, 128, float><<<N / 16, 128, 0, stream>>>(x, W1, hbuf);
  alpha_kernel<7, 16><<<(N * 7 + 255) / 256, 256, 0, stream>>>(hbuf, as1, ad1, als, ald, N);
  agg_kernel<7, 16, 1><<<(N + 3) / 4, 256, 0, stream>>>(hbuf, als, ald, rowptr, esorted, b1, x1h, N);
  // Layer 2: 112 -> 6x16
  gemm_kernel<112, 96, 128, __half><<<N / 16, 128, 0, stream>>>(x1h, W2, hbuf);
  alpha_kernel<6, 16><<<(N * 6 + 255) / 256, 256, 0, stream>>>(hbuf, as2, ad2, als, ald, N);
  agg_kernel<6, 16, 1><<<(N + 3) / 4, 256, 0, stream>>>(hbuf, als, ald, rowptr, esorted, b2, x2h, N);
  // Layer 3 (restructured): logits from x2, aggregate x2 per head, then per-head GEMM
  alpha3_kernel<<<(N * 6 + 255) / 256, 256, 0, stream>>>(x2h, ws3h, wd3h, als, ald, N);
  agg3x_kernel<<<(N + 3) / 4, 256, 0, stream>>>(x2h, als, ald, rowptr, esorted, g, N);
  gemm3h_kernel<<<dim3(N / 16, 6), 64, 0, stream>>>(g, W3, b3, out);
}

// Round 6
// 526.057 us; speedup vs baseline: 1.0365x; 1.0365x over previous
//
#include <hip/hip_runtime.h>
#include <hip/hip_fp16.h>
#include <cstdint>

#define NNODES 50000

__device__ inline void wave_lds_fence() {
  asm volatile("s_waitcnt lgkmcnt(0)" ::: "memory");
  __builtin_amdgcn_wave_barrier();
}

// ---------------- CSR build ----------------
__global__ void hist_kernel(const int* __restrict__ ei, int E, int Nn, int* __restrict__ cnt) {
  int i = blockIdx.x * blockDim.x + threadIdx.x;
  int ET = E + Nn;
  if (i >= ET) return;
  int d = (i < E) ? ei[E + i] : (i - E);
  atomicAdd(&cnt[d], 1);
}

__global__ void scan1_kernel(const int* __restrict__ in, int n, int* __restrict__ incl,
                             int* __restrict__ bsum) {
  __shared__ int sd[256];
  int g = blockIdx.x * 256 + threadIdx.x;
  int v = (g < n) ? in[g] : 0;
  sd[threadIdx.x] = v;
  __syncthreads();
  for (int off = 1; off < 256; off <<= 1) {
    int t = (threadIdx.x >= off) ? sd[threadIdx.x - off] : 0;
    __syncthreads();
    sd[threadIdx.x] += t;
    __syncthreads();
  }
  if (g < n) incl[g] = sd[threadIdx.x];
  if (threadIdx.x == 255) bsum[blockIdx.x] = sd[255];
}

__global__ void scan3_kernel(const int* __restrict__ incl, const int* __restrict__ bscan,
                             int n, int* __restrict__ rowptr) {
  int g = blockIdx.x * 256 + threadIdx.x;
  if (g == 0) rowptr[0] = 0;
  if (g < n) {
    int off = (blockIdx.x > 0) ? bscan[blockIdx.x - 1] : 0;
    rowptr[g + 1] = incl[g] + off;
  }
}

__global__ void scatter_kernel(const int* __restrict__ ei, int E, int Nn,
                               const int* __restrict__ rowptr, int* __restrict__ cnt2,
                               int* __restrict__ esorted) {
  int i = blockIdx.x * blockDim.x + threadIdx.x;
  int ET = E + Nn;
  if (i >= ET) return;
  int s, d;
  if (i < E) { s = ei[i]; d = ei[E + i]; }
  else       { s = i - E; d = i - E; }
  int pos = rowptr[d] + atomicAdd(&cnt2[d], 1);
  esorted[pos] = s;
}

// ---------------- GEMM: Hout[N,HC](fp16) = X[N,FIN] @ W[FIN,HC](fp32) ----------------
template <int FIN, int HC, int BLOCK, typename XT>
__global__ __launch_bounds__(BLOCK) void gemm_kernel(const XT* __restrict__ X,
                                                     const float* __restrict__ W,
                                                     __half* __restrict__ Hout) {
  constexpr int NT = 16;
  constexpr int TM = 4, TN = 4;
  constexpr int CG = HC / TN;
  __shared__ __align__(16) float xs[FIN * NT];  // [k][node]
  const int n0 = blockIdx.x * NT;
  if constexpr (sizeof(XT) == 4) {
    for (int i = threadIdx.x * 4; i < NT * FIN; i += BLOCK * 4) {
      float4 v = *(const float4*)((const float*)X + (size_t)n0 * FIN + i);
      int node = i / FIN, k = i % FIN;
      xs[(k + 0) * NT + node] = v.x;
      xs[(k + 1) * NT + node] = v.y;
      xs[(k + 2) * NT + node] = v.z;
      xs[(k + 3) * NT + node] = v.w;
    }
  } else {
    for (int i = threadIdx.x * 8; i < NT * FIN; i += BLOCK * 8) {
      union { uint4 u; __half2 h2[4]; } raw;
      raw.u = *(const uint4*)((const __half*)X + (size_t)n0 * FIN + i);
      int node = i / FIN, k = i % FIN;  // FIN%8==0 -> same node
#pragma unroll
      for (int j = 0; j < 4; ++j) {
        float2 f = __half22float2(raw.h2[j]);
        xs[(k + 2 * j + 0) * NT + node] = f.x;
        xs[(k + 2 * j + 1) * NT + node] = f.y;
      }
    }
  }
  __syncthreads();
  const int cg = threadIdx.x % CG;
  const int ng = threadIdx.x / CG;
  if (ng >= NT / TM) return;
  const int c0 = cg * TN;
  const int i0 = ng * TM;
  float acc[TM][TN];
#pragma unroll
  for (int i = 0; i < TM; ++i)
#pragma unroll
    for (int j = 0; j < TN; ++j) acc[i][j] = 0.f;
#pragma unroll 4
  for (int k = 0; k < FIN; ++k) {
    const float4 wv = *(const float4*)(W + (size_t)k * HC + c0);
    const float4 xv = *(const float4*)(xs + k * NT + i0);
    acc[0][0] += xv.x * wv.x; acc[0][1] += xv.x * wv.y; acc[0][2] += xv.x * wv.z; acc[0][3] += xv.x * wv.w;
    acc[1][0] += xv.y * wv.x; acc[1][1] += xv.y * wv.y; acc[1][2] += xv.y * wv.z; acc[1][3] += xv.y * wv.w;
    acc[2][0] += xv.z * wv.x; acc[2][1] += xv.z * wv.y; acc[2][2] += xv.z * wv.z; acc[2][3] += xv.z * wv.w;
    acc[3][0] += xv.w * wv.x; acc[3][1] += xv.w * wv.y; acc[3][2] += xv.w * wv.z; acc[3][3] += xv.w * wv.w;
  }
#pragma unroll
  for (int i = 0; i < TM; ++i) {
    union { __half2 h2[2]; uint2 u; } pk;
    pk.h2[0] = __floats2half2_rn(acc[i][0], acc[i][1]);
    pk.h2[1] = __floats2half2_rn(acc[i][2], acc[i][3]);
    *(uint2*)(Hout + (size_t)(n0 + i0 + i) * HC + c0) = pk.u;
  }
}

// ---------------- attention logits (reads fp16 h, writes stride-8 padded) ----------------
template <int H, int C>
__global__ void alpha_kernel(const __half* __restrict__ Hbuf, const float* __restrict__ a_s,
                             const float* __restrict__ a_d, float* __restrict__ als8,
                             float* __restrict__ ald8, int n_nodes) {
  int i = blockIdx.x * blockDim.x + threadIdx.x;
  if (i >= n_nodes * H) return;
  int n = i / H, h = i % H;
  const __half2* hp = (const __half2*)(Hbuf + (size_t)n * H * C + (size_t)h * C);
  float s1 = 0.f, s2 = 0.f;
#pragma unroll
  for (int c = 0; c < C / 2; ++c) {
    float2 f = __half22float2(hp[c]);
    s1 += f.x * a_s[h * C + 2 * c] + f.y * a_s[h * C + 2 * c + 1];
    s2 += f.x * a_d[h * C + 2 * c] + f.y * a_d[h * C + 2 * c + 1];
  }
  als8[n * 8 + h] = s1;
  ald8[n * 8 + h] = s2;
}

// ---------------- segment softmax + aggregate, layers 1-2 (one wave per dst) ----------------
// No max-subtraction: scores are O(+-5); exp() safe in fp32, result identical.
template <int H, int C, int RELU>
__global__ __launch_bounds__(256, 8) void agg_kernel(const __half* __restrict__ Hbuf,
                                                     const float* __restrict__ als8,
                                                     const float* __restrict__ ald8,
                                                     const int* __restrict__ rowptr,
                                                     const int* __restrict__ esrc,
                                                     const float* __restrict__ bias,
                                                     __half* __restrict__ Out, int n_nodes) {
  constexpr int HC = H * C;
  constexpr int PAIRS = HC / 2;  // <= 64
  constexpr int CP2 = C / 2;
  constexpr int UN = 8;          // edge-sweep unroll (MLP)
  constexpr int SW = H | 1;      // odd stride -> conflict-free LDS writes
  const int wave = threadIdx.x >> 6;
  const int lane = threadIdx.x & 63;
  const int n = blockIdx.x * 4 + wave;
  __shared__ float s_w[4][64 * SW];
  __shared__ int s_src[4][64];
  if (n >= n_nodes) return;

  const int e0 = rowptr[n];
  const int e1 = rowptr[n + 1];

  float aldn[H];
#pragma unroll
  for (int h = 0; h < H; ++h) aldn[h] = ald8[n * 8 + h];

  const int pj = lane;
  const int hd = pj / CP2;

  float acc0 = 0.f, acc1 = 0.f;
  float ls[H];
#pragma unroll
  for (int h = 0; h < H; ++h) ls[h] = 0.f;

  for (int base = e0; base < e1; base += 64) {
    const int cnt = (e1 - base < 64) ? (e1 - base) : 64;
    int sreg = 0;
    if (lane < cnt) sreg = esrc[base + lane];
    s_src[wave][lane] = sreg;
    if (lane < cnt) {
      const float4 qa = *(const float4*)(als8 + (size_t)sreg * 8);
      const float4 qb = *(const float4*)(als8 + (size_t)sreg * 8 + 4);
      const float q[8] = {qa.x, qa.y, qa.z, qa.w, qb.x, qb.y, qb.z, qb.w};
#pragma unroll
      for (int h = 0; h < H; ++h) {
        float v = q[h] + aldn[h];
        v = v > 0.f ? v : 0.2f * v;  // leaky_relu 0.2
        float w = __expf(v);
        ls[h] += w;
        s_w[wave][lane * SW + h] = w;
      }
    } else {
#pragma unroll
      for (int h = 0; h < H; ++h) s_w[wave][lane * SW + h] = 0.f;
    }
    wave_lds_fence();
    if (pj < PAIRS) {
      for (int t = 0; t < cnt; t += UN) {
        int so[UN];
#pragma unroll
        for (int k = 0; k < UN; ++k) so[k] = s_src[wave][t + k] * HC;
        __half2 f[UN];
#pragma unroll
        for (int k = 0; k < UN; ++k) f[k] = *(const __half2*)(Hbuf + so[k] + 2 * pj);
#pragma unroll
        for (int k = 0; k < UN; ++k) {
          float w = s_w[wave][(t + k) * SW + hd];
          float2 ff = __half22float2(f[k]);
          acc0 += w * ff.x;
          acc1 += w * ff.y;
        }
      }
    }
    wave_lds_fence();
  }
  // reduce per-head weight sums across the wave (each lane held its own edges' w)
#pragma unroll
  for (int h = 0; h < H; ++h) {
    float v = ls[h];
#pragma unroll
    for (int off = 32; off > 0; off >>= 1) v += __shfl_xor(v, off, 64);
    ls[h] = v;
  }
  if (pj < PAIRS) {
    float inv = 1.f / ls[hd];
    float2 bv = *(const float2*)(bias + 2 * pj);
    float o0 = acc0 * inv + bv.x;
    float o1 = acc1 * inv + bv.y;
    if (RELU) { o0 = fmaxf(o0, 0.f); o1 = fmaxf(o1, 0.f); }
    *(__half2*)(Out + (size_t)n * HC + 2 * pj) = __floats2half2_rn(o0, o1);
  }
}

// ---------------- layer-3 prep: ws3h[h][k] = sum_c W3[k, h*40+c]*a_src3[h,c] ----------------
__global__ void prep3_kernel(const float* __restrict__ W3, const float* __restrict__ as3,
                             const float* __restrict__ ad3, float* __restrict__ ws3h,
                             float* __restrict__ wd3h) {
  int h = blockIdx.x, k = threadIdx.x;  // 6 x 96
  float s1 = 0.f, s2 = 0.f;
  for (int c = 0; c < 40; ++c) {
    float w = W3[k * 240 + h * 40 + c];
    s1 += w * as3[h * 40 + c];
    s2 += w * ad3[h * 40 + c];
  }
  ws3h[h * 96 + k] = s1;
  wd3h[h * 96 + k] = s2;
}

// ---------------- layer-3 logits from x2 directly ----------------
__global__ void alpha3_kernel(const __half* __restrict__ X2h, const float* __restrict__ ws3h,
                              const float* __restrict__ wd3h, float* __restrict__ als8,
                              float* __restrict__ ald8, int n_nodes) {
  int i = blockIdx.x * blockDim.x + threadIdx.x;
  if (i >= n_nodes * 6) return;
  int n = i / 6, h = i % 6;
  const __half2* xp = (const __half2*)(X2h + (size_t)n * 96);
  const float* sp = ws3h + h * 96;
  const float* dp = wd3h + h * 96;
  float s1 = 0.f, s2 = 0.f;
#pragma unroll
  for (int c = 0; c < 48; ++c) {
    float2 f = __half22float2(xp[c]);
    s1 += f.x * sp[2 * c] + f.y * sp[2 * c + 1];
    s2 += f.x * dp[2 * c] + f.y * dp[2 * c + 1];
  }
  als8[n * 8 + h] = s1;
  ald8[n * 8 + h] = s2;
}

// ---------------- layer-3 aggregation in x2-space: g[n,h,:] = sum_e alpha_eh * x2[src_e] ----------------
// (256,4): 128-reg budget -> no scratch spills (the (256,8) 64-reg budget spilled: r5 WRITE 250MB)
__global__ __launch_bounds__(256, 4) void agg3x_kernel(const __half* __restrict__ X2h,
                                                       const float* __restrict__ als8,
                                                       const float* __restrict__ ald8,
                                                       const int* __restrict__ rowptr,
                                                       const int* __restrict__ esrc,
                                                       __half* __restrict__ G, int n_nodes) {
  constexpr int H = 6, CIN = 96, P = 48, UN = 8;
  constexpr int SW = 9;  // odd stride -> conflict-free LDS writes
  const int wave = threadIdx.x >> 6;
  const int lane = threadIdx.x & 63;
  const int n = blockIdx.x * 4 + wave;
  __shared__ float s_w[4][64 * SW];
  __shared__ int s_src[4][64];
  if (n >= n_nodes) return;

  const int e0 = rowptr[n];
  const int e1 = rowptr[n + 1];

  float aldn[H];
#pragma unroll
  for (int h = 0; h < H; ++h) aldn[h] = ald8[n * 8 + h];

  float acc0[H], acc1[H], ls[H];
#pragma unroll
  for (int h = 0; h < H; ++h) { acc0[h] = 0.f; acc1[h] = 0.f; ls[h] = 0.f; }

  for (int base = e0; base < e1; base += 64) {
    const int cnt = (e1 - base < 64) ? (e1 - base) : 64;
    int sreg = 0;
    if (lane < cnt) sreg = esrc[base + lane];
    s_src[wave][lane] = sreg;
    if (lane < cnt) {
      const float4 qa = *(const float4*)(als8 + (size_t)sreg * 8);
      const float2 qb = *(const float2*)(als8 + (size_t)sreg * 8 + 4);
      const float q[6] = {qa.x, qa.y, qa.z, qa.w, qb.x, qb.y};
#pragma unroll
      for (int h = 0; h < H; ++h) {
        float v = q[h] + aldn[h];
        v = v > 0.f ? v : 0.2f * v;
        float w = __expf(v);
        ls[h] += w;
        s_w[wave][lane * SW + h] = w;
      }
    } else {
#pragma unroll
      for (int h = 0; h < H; ++h) s_w[wave][lane * SW + h] = 0.f;
    }
    wave_lds_fence();
    if (lane < P) {
      for (int t = 0; t < cnt; t += UN) {
        int so[UN];
#pragma unroll
        for (int k = 0; k < UN; ++k) so[k] = s_src[wave][t + k] * CIN;
        __half2 f[UN];
#pragma unroll
        for (int k = 0; k < UN; ++k) f[k] = *(const __half2*)(X2h + so[k] + 2 * lane);
#pragma unroll
        for (int k = 0; k < UN; ++k) {
          const float* wp = &s_w[wave][(t + k) * SW];
          float2 ff = __half22float2(f[k]);
#pragma unroll
          for (int h = 0; h < H; ++h) {
            float w = wp[h];  // scalar LDS broadcast
            acc0[h] += w * ff.x;
            acc1[h] += w * ff.y;
          }
        }
      }
    }
    wave_lds_fence();
  }
#pragma unroll
  for (int h = 0; h < H; ++h) {
    float v = ls[h];
#pragma unroll
    for (int off = 32; off > 0; off >>= 1) v += __shfl_xor(v, off, 64);
    ls[h] = 1.f / v;
  }
  if (lane < P) {
#pragma unroll
    for (int h = 0; h < H; ++h) {
      union { __half2 h2; uint u; } cv;
      cv.h2 = __floats2half2_rn(acc0[h] * ls[h], acc1[h] * ls[h]);
      // nontemporal: G streams to gemm3h later; keep it out of L2 to protect x2h locality
      __builtin_nontemporal_store(cv.u, (uint*)(G + (size_t)n * 576 + h * 96 + 2 * lane));
    }
  }
}

// ---------------- layer-3 per-head GEMM: out[:, h*40:+40] = g[:,h,:] @ W3[:, h*40:+40] + b ----------------
__global__ __launch_bounds__(64) void gemm3h_kernel(const __half* __restrict__ G,
                                                    const float* __restrict__ W3,
                                                    const float* __restrict__ b3,
                                                    float* __restrict__ Out) {
  constexpr int NT = 16, TM = 4, TN = 4, CG = 10;
  const int h = blockIdx.y;
  __shared__ __align__(16) float xs[96 * NT];
  const int n0 = blockIdx.x * NT;
  for (int i = threadIdx.x * 8; i < NT * 96; i += 64 * 8) {
    int node = i / 96, k = i % 96;  // 96%8==0
    union { uint4 u; __half2 h2[4]; } raw;
    raw.u = *(const uint4*)(G + (size_t)(n0 + node) * 576 + h * 96 + k);
#pragma unroll
    for (int j = 0; j < 4; ++j) {
      float2 f = __half22float2(raw.h2[j]);
      xs[(k + 2 * j + 0) * NT + node] = f.x;
      xs[(k + 2 * j + 1) * NT + node] = f.y;
    }
  }
  __syncthreads();
  const int cg = threadIdx.x % CG;
  const int ng = threadIdx.x / CG;
  if (ng >= NT / TM) return;
  const int c0 = cg * TN;
  const int i0 = ng * TM;
  float acc[TM][TN];
#pragma unroll
  for (int i = 0; i < TM; ++i)
#pragma unroll
    for (int j = 0; j < TN; ++j) acc[i][j] = 0.f;
#pragma unroll 4
  for (int k = 0; k < 96; ++k) {
    const float4 wv = *(const float4*)(W3 + (size_t)k * 240 + h * 40 + c0);
    const float4 xv = *(const float4*)(xs + k * NT + i0);
    acc[0][0] += xv.x * wv.x; acc[0][1] += xv.x * wv.y; acc[0][2] += xv.x * wv.z; acc[0][3] += xv.x * wv.w;
    acc[1][0] += xv.y * wv.x; acc[1][1] += xv.y * wv.y; acc[1][2] += xv.y * wv.z; acc[1][3] += xv.y * wv.w;
    acc[2][0] += xv.z * wv.x; acc[2][1] += xv.z * wv.y; acc[2][2] += xv.z * wv.z; acc[2][3] += xv.z * wv.w;
    acc[3][0] += xv.w * wv.x; acc[3][1] += xv.w * wv.y; acc[3][2] += xv.w * wv.z; acc[3][3] += xv.w * wv.w;
  }
  const float4 bv = *(const float4*)(b3 + h * 40 + c0);
#pragma unroll
  for (int i = 0; i < TM; ++i) {
    float4 o;
    o.x = acc[i][0] + bv.x; o.y = acc[i][1] + bv.y;
    o.z = acc[i][2] + bv.z; o.w = acc[i][3] + bv.w;
    *(float4*)(Out + (size_t)(n0 + i0 + i) * 240 + h * 40 + c0) = o;
  }
}

// ---------------- launch ----------------
extern "C" void kernel_launch(void* const* d_in, const int* in_sizes, int n_in,
                              void* d_out, int out_size, void* d_ws, size_t ws_size,
                              hipStream_t stream) {
  const int N = NNODES;
  const float* x  = (const float*)d_in[0];
  const int* ei   = (const int*)d_in[1];
  const float* W1 = (const float*)d_in[2];
  const float* as1 = (const float*)d_in[3];
  const float* ad1 = (const float*)d_in[4];
  const float* b1  = (const float*)d_in[5];
  const float* W2  = (const float*)d_in[6];
  const float* as2 = (const float*)d_in[7];
  const float* ad2 = (const float*)d_in[8];
  const float* b2  = (const float*)d_in[9];
  const float* W3  = (const float*)d_in[10];
  const float* as3 = (const float*)d_in[11];
  const float* ad3 = (const float*)d_in[12];
  const float* b3  = (const float*)d_in[13];
  float* out = (float*)d_out;
  const int E = in_sizes[1] / 2;
  const int ET = E + N;

  char* ws = (char*)d_ws;
  size_t off = 0;
  auto alloc = [&](size_t bytes) -> char* {
    char* p = ws + off;
    off += (bytes + 255) & ~(size_t)255;
    return p;
  };
  int* cnt     = (int*)alloc((size_t)N * 4);
  int* cnt2    = (int*)alloc((size_t)N * 4);
  int* incl    = (int*)alloc((size_t)N * 4);
  int* bsum    = (int*)alloc(512 * 4);
  int* bscan   = (int*)alloc(256 * 4);
  int* rowptr  = (int*)alloc((size_t)(N + 1) * 4);
  int* esorted = (int*)alloc((size_t)ET * 4);
  float* als   = (float*)alloc((size_t)N * 8 * 4);
  float* ald   = (float*)alloc((size_t)N * 8 * 4);
  float* ws3h  = (float*)alloc(6 * 96 * 4);
  float* wd3h  = (float*)alloc(6 * 96 * 4);
  __half* x2h  = (__half*)alloc((size_t)N * 96 * 2);
  // g-region (57.6 MB); x1h and hbuf alias its front (dead before agg3x writes g)
  __half* g    = (__half*)alloc((size_t)N * 576 * 2);
  __half* x1h  = g;                                   // N*112*2 = 11.2 MB
  __half* hbuf = g + (size_t)N * 112;                 // N*112*2 = 11.2 MB (h1 112ch / h2 96ch)

  hipMemsetAsync(cnt, 0, (size_t)N * 4, stream);
  hipMemsetAsync(cnt2, 0, (size_t)N * 4, stream);

  const int B1 = (N + 255) / 256;
  hist_kernel<<<(ET + 255) / 256, 256, 0, stream>>>(ei, E, N, cnt);
  scan1_kernel<<<B1, 256, 0, stream>>>(cnt, N, incl, bsum);
  scan1_kernel<<<1, 256, 0, stream>>>(bsum, B1, bscan, bsum + 256);
  scan3_kernel<<<B1, 256, 0, stream>>>(incl, bscan, N, rowptr);
  scatter_kernel<<<(ET + 255) / 256, 256, 0, stream>>>(ei, E, N, rowptr, cnt2, esorted);
  prep3_kernel<<<6, 96, 0, stream>>>(W3, as3, ad3, ws3h, wd3h);

  // Layer 1: 128 -> 7x16
  gemm_kernel<128, 112, 128, float><<<N / 16, 128, 0, stream>>>(x, W1, hbuf);
  alpha_kernel<7, 16><<<(N * 7 + 255) / 256, 256, 0, stream>>>(hbuf, as1, ad1, als, ald, N);
  agg_kernel<7, 16, 1><<<(N + 3) / 4, 256, 0, stream>>>(hbuf, als, ald, rowptr, esorted, b1, x1h, N);
  // Layer 2: 112 -> 6x16
  gemm_kernel<112, 96, 128, __half><<<N / 16, 128, 0, stream>>>(x1h, W2, hbuf);
  alpha_kernel<6, 16><<<(N * 6 + 255) / 256, 256, 0, stream>>>(hbuf, as2, ad2, als, ald, N);
  agg_kernel<6, 16, 1><<<(N + 3) / 4, 256, 0, stream>>>(hbuf, als, ald, rowptr, esorted, b2, x2h, N);
  // Layer 3 (restructured): logits from x2, aggregate x2 per head, then per-head GEMM
  alpha3_kernel<<<(N * 6 + 255) / 256, 256, 0, stream>>>(x2h, ws3h, wd3h, als, ald, N);
  agg3x_kernel<<<(N + 3) / 4, 256, 0, stream>>>(x2h, als, ald, rowptr, esorted, g, N);
  gemm3h_kernel<<<dim3(N / 16, 6), 64, 0, stream>>>(g, W3, b3, out);
}

// Round 7
// 521.410 us; speedup vs baseline: 1.0457x; 1.0089x over previous
//
#include <hip/hip_runtime.h>
#include <hip/hip_fp16.h>
#include <cstdint>

#define NNODES 50000

__device__ inline void wave_lds_fence() {
  asm volatile("s_waitcnt lgkmcnt(0)" ::: "memory");
  __builtin_amdgcn_wave_barrier();
}

// ---------------- CSR build ----------------
__global__ void hist_kernel(const int* __restrict__ ei, int E, int Nn, int* __restrict__ cnt) {
  int i = blockIdx.x * blockDim.x + threadIdx.x;
  int ET = E + Nn;
  if (i >= ET) return;
  int d = (i < E) ? ei[E + i] : (i - E);
  atomicAdd(&cnt[d], 1);
}

__global__ void scan1_kernel(const int* __restrict__ in, int n, int* __restrict__ incl,
                             int* __restrict__ bsum) {
  __shared__ int sd[256];
  int g = blockIdx.x * 256 + threadIdx.x;
  int v = (g < n) ? in[g] : 0;
  sd[threadIdx.x] = v;
  __syncthreads();
  for (int off = 1; off < 256; off <<= 1) {
    int t = (threadIdx.x >= off) ? sd[threadIdx.x - off] : 0;
    __syncthreads();
    sd[threadIdx.x] += t;
    __syncthreads();
  }
  if (g < n) incl[g] = sd[threadIdx.x];
  if (threadIdx.x == 255) bsum[blockIdx.x] = sd[255];
}

__global__ void scan3_kernel(const int* __restrict__ incl, const int* __restrict__ bscan,
                             int n, int* __restrict__ rowptr) {
  int g = blockIdx.x * 256 + threadIdx.x;
  if (g == 0) rowptr[0] = 0;
  if (g < n) {
    int off = (blockIdx.x > 0) ? bscan[blockIdx.x - 1] : 0;
    rowptr[g + 1] = incl[g] + off;
  }
}

__global__ void scatter_kernel(const int* __restrict__ ei, int E, int Nn,
                               const int* __restrict__ rowptr, int* __restrict__ cnt2,
                               int* __restrict__ esorted) {
  int i = blockIdx.x * blockDim.x + threadIdx.x;
  int ET = E + Nn;
  if (i >= ET) return;
  int s, d;
  if (i < E) { s = ei[i]; d = ei[E + i]; }
  else       { s = i - E; d = i - E; }
  int pos = rowptr[d] + atomicAdd(&cnt2[d], 1);
  esorted[pos] = s;
}

// ---------------- GEMM: Hout[N,HC](fp16) = X[N,FIN] @ W[FIN,HC](fp32) ----------------
template <int FIN, int HC, int BLOCK, typename XT>
__global__ __launch_bounds__(BLOCK) void gemm_kernel(const XT* __restrict__ X,
                                                     const float* __restrict__ W,
                                                     __half* __restrict__ Hout) {
  constexpr int NT = 16;
  constexpr int TM = 4, TN = 4;
  constexpr int CG = HC / TN;
  __shared__ __align__(16) float xs[FIN * NT];  // [k][node]
  const int n0 = blockIdx.x * NT;
  if constexpr (sizeof(XT) == 4) {
    for (int i = threadIdx.x * 4; i < NT * FIN; i += BLOCK * 4) {
      float4 v = *(const float4*)((const float*)X + (size_t)n0 * FIN + i);
      int node = i / FIN, k = i % FIN;
      xs[(k + 0) * NT + node] = v.x;
      xs[(k + 1) * NT + node] = v.y;
      xs[(k + 2) * NT + node] = v.z;
      xs[(k + 3) * NT + node] = v.w;
    }
  } else {
    for (int i = threadIdx.x * 8; i < NT * FIN; i += BLOCK * 8) {
      union { uint4 u; __half2 h2[4]; } raw;
      raw.u = *(const uint4*)((const __half*)X + (size_t)n0 * FIN + i);
      int node = i / FIN, k = i % FIN;  // FIN%8==0 -> same node
#pragma unroll
      for (int j = 0; j < 4; ++j) {
        float2 f = __half22float2(raw.h2[j]);
        xs[(k + 2 * j + 0) * NT + node] = f.x;
        xs[(k + 2 * j + 1) * NT + node] = f.y;
      }
    }
  }
  __syncthreads();
  const int cg = threadIdx.x % CG;
  const int ng = threadIdx.x / CG;
  if (ng >= NT / TM) return;
  const int c0 = cg * TN;
  const int i0 = ng * TM;
  float acc[TM][TN];
#pragma unroll
  for (int i = 0; i < TM; ++i)
#pragma unroll
    for (int j = 0; j < TN; ++j) acc[i][j] = 0.f;
#pragma unroll 4
  for (int k = 0; k < FIN; ++k) {
    const float4 wv = *(const float4*)(W + (size_t)k * HC + c0);
    const float4 xv = *(const float4*)(xs + k * NT + i0);
    acc[0][0] += xv.x * wv.x; acc[0][1] += xv.x * wv.y; acc[0][2] += xv.x * wv.z; acc[0][3] += xv.x * wv.w;
    acc[1][0] += xv.y * wv.x; acc[1][1] += xv.y * wv.y; acc[1][2] += xv.y * wv.z; acc[1][3] += xv.y * wv.w;
    acc[2][0] += xv.z * wv.x; acc[2][1] += xv.z * wv.y; acc[2][2] += xv.z * wv.z; acc[2][3] += xv.z * wv.w;
    acc[3][0] += xv.w * wv.x; acc[3][1] += xv.w * wv.y; acc[3][2] += xv.w * wv.z; acc[3][3] += xv.w * wv.w;
  }
#pragma unroll
  for (int i = 0; i < TM; ++i) {
    union { __half2 h2[2]; uint2 u; } pk;
    pk.h2[0] = __floats2half2_rn(acc[i][0], acc[i][1]);
    pk.h2[1] = __floats2half2_rn(acc[i][2], acc[i][3]);
    *(uint2*)(Hout + (size_t)(n0 + i0 + i) * HC + c0) = pk.u;
  }
}

// ---------------- attention logits (reads fp16 h, writes stride-8 padded) ----------------
template <int H, int C>
__global__ void alpha_kernel(const __half* __restrict__ Hbuf, const float* __restrict__ a_s,
                             const float* __restrict__ a_d, float* __restrict__ als8,
                             float* __restrict__ ald8, int n_nodes) {
  int i = blockIdx.x * blockDim.x + threadIdx.x;
  if (i >= n_nodes * H) return;
  int n = i / H, h = i % H;
  const __half2* hp = (const __half2*)(Hbuf + (size_t)n * H * C + (size_t)h * C);
  float s1 = 0.f, s2 = 0.f;
#pragma unroll
  for (int c = 0; c < C / 2; ++c) {
    float2 f = __half22float2(hp[c]);
    s1 += f.x * a_s[h * C + 2 * c] + f.y * a_s[h * C + 2 * c + 1];
    s2 += f.x * a_d[h * C + 2 * c] + f.y * a_d[h * C + 2 * c + 1];
  }
  als8[n * 8 + h] = s1;
  ald8[n * 8 + h] = s2;
}

// ---------------- segment softmax + aggregate, layers 1-2 (one wave per dst) ----------------
// No max-subtraction: scores are O(+-5); exp() safe in fp32, result identical.
template <int H, int C, int RELU>
__global__ __launch_bounds__(256, 8) void agg_kernel(const __half* __restrict__ Hbuf,
                                                     const float* __restrict__ als8,
                                                     const float* __restrict__ ald8,
                                                     const int* __restrict__ rowptr,
                                                     const int* __restrict__ esrc,
                                                     const float* __restrict__ bias,
                                                     __half* __restrict__ Out, int n_nodes) {
  constexpr int HC = H * C;
  constexpr int PAIRS = HC / 2;  // <= 64
  constexpr int CP2 = C / 2;
  constexpr int UN = 8;          // edge-sweep unroll (MLP)
  constexpr int SW = H | 1;      // odd stride -> conflict-free LDS writes
  const int wave = threadIdx.x >> 6;
  const int lane = threadIdx.x & 63;
  const int n = blockIdx.x * 4 + wave;
  __shared__ float s_w[4][64 * SW];
  __shared__ int s_src[4][64];
  if (n >= n_nodes) return;

  const int e0 = rowptr[n];
  const int e1 = rowptr[n + 1];

  float aldn[H];
#pragma unroll
  for (int h = 0; h < H; ++h) aldn[h] = ald8[n * 8 + h];

  const int pj = lane;
  const int hd = pj / CP2;

  float acc0 = 0.f, acc1 = 0.f;
  float ls[H];
#pragma unroll
  for (int h = 0; h < H; ++h) ls[h] = 0.f;

  for (int base = e0; base < e1; base += 64) {
    const int cnt = (e1 - base < 64) ? (e1 - base) : 64;
    int sreg = 0;
    if (lane < cnt) sreg = esrc[base + lane];
    s_src[wave][lane] = sreg;
    if (lane < cnt) {
      const float4 qa = *(const float4*)(als8 + (size_t)sreg * 8);
      const float4 qb = *(const float4*)(als8 + (size_t)sreg * 8 + 4);
      const float q[8] = {qa.x, qa.y, qa.z, qa.w, qb.x, qb.y, qb.z, qb.w};
#pragma unroll
      for (int h = 0; h < H; ++h) {
        float v = q[h] + aldn[h];
        v = v > 0.f ? v : 0.2f * v;  // leaky_relu 0.2
        float w = __expf(v);
        ls[h] += w;
        s_w[wave][lane * SW + h] = w;
      }
    } else {
#pragma unroll
      for (int h = 0; h < H; ++h) s_w[wave][lane * SW + h] = 0.f;
    }
    wave_lds_fence();
    if (pj < PAIRS) {
      for (int t = 0; t < cnt; t += UN) {
        int so[UN];
#pragma unroll
        for (int k = 0; k < UN; ++k) so[k] = s_src[wave][t + k] * HC;
        __half2 f[UN];
#pragma unroll
        for (int k = 0; k < UN; ++k) f[k] = *(const __half2*)(Hbuf + so[k] + 2 * pj);
#pragma unroll
        for (int k = 0; k < UN; ++k) {
          float w = s_w[wave][(t + k) * SW + hd];
          float2 ff = __half22float2(f[k]);
          acc0 += w * ff.x;
          acc1 += w * ff.y;
        }
      }
    }
    wave_lds_fence();
  }
  // reduce per-head weight sums across the wave (each lane held its own edges' w)
#pragma unroll
  for (int h = 0; h < H; ++h) {
    float v = ls[h];
#pragma unroll
    for (int off = 32; off > 0; off >>= 1) v += __shfl_xor(v, off, 64);
    ls[h] = v;
  }
  if (pj < PAIRS) {
    float inv = 1.f / ls[hd];
    float2 bv = *(const float2*)(bias + 2 * pj);
    float o0 = acc0 * inv + bv.x;
    float o1 = acc1 * inv + bv.y;
    if (RELU) { o0 = fmaxf(o0, 0.f); o1 = fmaxf(o1, 0.f); }
    *(__half2*)(Out + (size_t)n * HC + 2 * pj) = __floats2half2_rn(o0, o1);
  }
}

// ---------------- layer-3 prep: ws3h[h][k] = sum_c W3[k, h*40+c]*a_src3[h,c] ----------------
__global__ void prep3_kernel(const float* __restrict__ W3, const float* __restrict__ as3,
                             const float* __restrict__ ad3, float* __restrict__ ws3h,
                             float* __restrict__ wd3h) {
  int h = blockIdx.x, k = threadIdx.x;  // 6 x 96
  float s1 = 0.f, s2 = 0.f;
  for (int c = 0; c < 40; ++c) {
    float w = W3[k * 240 + h * 40 + c];
    s1 += w * as3[h * 40 + c];
    s2 += w * ad3[h * 40 + c];
  }
  ws3h[h * 96 + k] = s1;
  wd3h[h * 96 + k] = s2;
}

// ---------------- layer-3 logits from x2 directly ----------------
__global__ void alpha3_kernel(const __half* __restrict__ X2h, const float* __restrict__ ws3h,
                              const float* __restrict__ wd3h, float* __restrict__ als8,
                              float* __restrict__ ald8, int n_nodes) {
  int i = blockIdx.x * blockDim.x + threadIdx.x;
  if (i >= n_nodes * 6) return;
  int n = i / 6, h = i % 6;
  const __half2* xp = (const __half2*)(X2h + (size_t)n * 96);
  const float* sp = ws3h + h * 96;
  const float* dp = wd3h + h * 96;
  float s1 = 0.f, s2 = 0.f;
#pragma unroll
  for (int c = 0; c < 48; ++c) {
    float2 f = __half22float2(xp[c]);
    s1 += f.x * sp[2 * c] + f.y * sp[2 * c + 1];
    s2 += f.x * dp[2 * c] + f.y * dp[2 * c + 1];
  }
  als8[n * 8 + h] = s1;
  ald8[n * 8 + h] = s2;
}

// ---------------- layer-3 aggregation in x2-space: g[n,h,:] = sum_e alpha_eh * x2[src_e] ----------------
// (256,4): 128-reg budget -> no scratch spills (the (256,8) 64-reg budget spilled: r5 WRITE 250MB)
__global__ __launch_bounds__(256, 4) void agg3x_kernel(const __half* __restrict__ X2h,
                                                       const float* __restrict__ als8,
                                                       const float* __restrict__ ald8,
                                                       const int* __restrict__ rowptr,
                                                       const int* __restrict__ esrc,
                                                       __half* __restrict__ G, int n_nodes) {
  constexpr int H = 6, CIN = 96, P = 48, UN = 8;
  constexpr int SW = 9;  // odd stride -> conflict-free LDS writes
  const int wave = threadIdx.x >> 6;
  const int lane = threadIdx.x & 63;
  const int n = blockIdx.x * 4 + wave;
  __shared__ float s_w[4][64 * SW];
  __shared__ int s_src[4][64];
  if (n >= n_nodes) return;

  const int e0 = rowptr[n];
  const int e1 = rowptr[n + 1];

  float aldn[H];
#pragma unroll
  for (int h = 0; h < H; ++h) aldn[h] = ald8[n * 8 + h];

  float acc0[H], acc1[H], ls[H];
#pragma unroll
  for (int h = 0; h < H; ++h) { acc0[h] = 0.f; acc1[h] = 0.f; ls[h] = 0.f; }

  for (int base = e0; base < e1; base += 64) {
    const int cnt = (e1 - base < 64) ? (e1 - base) : 64;
    int sreg = 0;
    if (lane < cnt) sreg = esrc[base + lane];
    s_src[wave][lane] = sreg;
    if (lane < cnt) {
      const float4 qa = *(const float4*)(als8 + (size_t)sreg * 8);
      const float2 qb = *(const float2*)(als8 + (size_t)sreg * 8 + 4);
      const float q[6] = {qa.x, qa.y, qa.z, qa.w, qb.x, qb.y};
#pragma unroll
      for (int h = 0; h < H; ++h) {
        float v = q[h] + aldn[h];
        v = v > 0.f ? v : 0.2f * v;
        float w = __expf(v);
        ls[h] += w;
        s_w[wave][lane * SW + h] = w;
      }
    } else {
#pragma unroll
      for (int h = 0; h < H; ++h) s_w[wave][lane * SW + h] = 0.f;
    }
    wave_lds_fence();
    if (lane < P) {
      for (int t = 0; t < cnt; t += UN) {
        int so[UN];
#pragma unroll
        for (int k = 0; k < UN; ++k) so[k] = s_src[wave][t + k] * CIN;
        __half2 f[UN];
#pragma unroll
        for (int k = 0; k < UN; ++k) f[k] = *(const __half2*)(X2h + so[k] + 2 * lane);
#pragma unroll
        for (int k = 0; k < UN; ++k) {
          const float* wp = &s_w[wave][(t + k) * SW];
          float2 ff = __half22float2(f[k]);
#pragma unroll
          for (int h = 0; h < H; ++h) {
            float w = wp[h];  // scalar LDS broadcast
            acc0[h] += w * ff.x;
            acc1[h] += w * ff.y;
          }
        }
      }
    }
    wave_lds_fence();
  }
#pragma unroll
  for (int h = 0; h < H; ++h) {
    float v = ls[h];
#pragma unroll
    for (int off = 32; off > 0; off >>= 1) v += __shfl_xor(v, off, 64);
    ls[h] = 1.f / v;
  }
  if (lane < P) {
#pragma unroll
    for (int h = 0; h < H; ++h) {
      *(__half2*)(G + (size_t)n * 576 + h * 96 + 2 * lane) =
          __floats2half2_rn(acc0[h] * ls[h], acc1[h] * ls[h]);
    }
  }
}

// ---------------- layer-3 output GEMM: out[16 nodes, 240 cols] per block ----------------
// Block-diagonal: col c uses G[:, (c/40)*96 .. +96]. 4-col groups never cross a head
// boundary (40%4==0), so each thread's k-window is a single head slice.
__global__ __launch_bounds__(256) void gemm3h_kernel(const __half* __restrict__ G,
                                                     const float* __restrict__ W3,
                                                     const float* __restrict__ b3,
                                                     float* __restrict__ Out) {
  constexpr int NT = 16, NP = 20;  // node dim padded 16->20: float4-aligned, conflict-benign
  __shared__ __align__(16) float xs[576 * NP];  // [k576][node]
  const int n0 = blockIdx.x * NT;
  const int t = threadIdx.x;
  // stage 16 full G rows (1152 B each, fully coalesced)
  for (int i = t * 8; i < NT * 576; i += 256 * 8) {
    int node = i / 576, k = i % 576;  // 576%8==0 -> same node
    union { uint4 u; __half2 h2[4]; } raw;
    raw.u = *(const uint4*)(G + (size_t)(n0 + node) * 576 + k);
#pragma unroll
    for (int j = 0; j < 4; ++j) {
      float2 f = __half22float2(raw.h2[j]);
      xs[(k + 2 * j + 0) * NP + node] = f.x;
      xs[(k + 2 * j + 1) * NP + node] = f.y;
    }
  }
  __syncthreads();
  if (t >= 240) return;
  const int cg = t % 60;            // 60 col groups x 4 cols = 240 cols
  const int ng = t / 60;            // 4 node groups x 4 nodes
  const int c0 = cg * 4;
  const int i0 = ng * 4;
  const int kbase = (c0 / 40) * 96; // head slice of G
  float acc[4][4];
#pragma unroll
  for (int i = 0; i < 4; ++i)
#pragma unroll
    for (int j = 0; j < 4; ++j) acc[i][j] = 0.f;
#pragma unroll 4
  for (int k = 0; k < 96; ++k) {
    const float4 wv = *(const float4*)(W3 + (size_t)k * 240 + c0);
    const float4 xv = *(const float4*)(xs + (kbase + k) * NP + i0);
    acc[0][0] += xv.x * wv.x; acc[0][1] += xv.x * wv.y; acc[0][2] += xv.x * wv.z; acc[0][3] += xv.x * wv.w;
    acc[1][0] += xv.y * wv.x; acc[1][1] += xv.y * wv.y; acc[1][2] += xv.y * wv.z; acc[1][3] += xv.y * wv.w;
    acc[2][0] += xv.z * wv.x; acc[2][1] += xv.z * wv.y; acc[2][2] += xv.z * wv.z; acc[2][3] += xv.z * wv.w;
    acc[3][0] += xv.w * wv.x; acc[3][1] += xv.w * wv.y; acc[3][2] += xv.w * wv.z; acc[3][3] += xv.w * wv.w;
  }
  const float4 bv = *(const float4*)(b3 + c0);
#pragma unroll
  for (int i = 0; i < 4; ++i) {
    float4 o;
    o.x = acc[i][0] + bv.x; o.y = acc[i][1] + bv.y;
    o.z = acc[i][2] + bv.z; o.w = acc[i][3] + bv.w;
    *(float4*)(Out + (size_t)(n0 + i0 + i) * 240 + c0) = o;
  }
}

// ---------------- launch ----------------
extern "C" void kernel_launch(void* const* d_in, const int* in_sizes, int n_in,
                              void* d_out, int out_size, void* d_ws, size_t ws_size,
                              hipStream_t stream) {
  const int N = NNODES;
  const float* x  = (const float*)d_in[0];
  const int* ei   = (const int*)d_in[1];
  const float* W1 = (const float*)d_in[2];
  const float* as1 = (const float*)d_in[3];
  const float* ad1 = (const float*)d_in[4];
  const float* b1  = (const float*)d_in[5];
  const float* W2  = (const float*)d_in[6];
  const float* as2 = (const float*)d_in[7];
  const float* ad2 = (const float*)d_in[8];
  const float* b2  = (const float*)d_in[9];
  const float* W3  = (const float*)d_in[10];
  const float* as3 = (const float*)d_in[11];
  const float* ad3 = (const float*)d_in[12];
  const float* b3  = (const float*)d_in[13];
  float* out = (float*)d_out;
  const int E = in_sizes[1] / 2;
  const int ET = E + N;

  char* ws = (char*)d_ws;
  size_t off = 0;
  auto alloc = [&](size_t bytes) -> char* {
    char* p = ws + off;
    off += (bytes + 255) & ~(size_t)255;
    return p;
  };
  int* cnt     = (int*)alloc((size_t)N * 4);
  int* cnt2    = (int*)alloc((size_t)N * 4);
  int* incl    = (int*)alloc((size_t)N * 4);
  int* bsum    = (int*)alloc(512 * 4);
  int* bscan   = (int*)alloc(256 * 4);
  int* rowptr  = (int*)alloc((size_t)(N + 1) * 4);
  int* esorted = (int*)alloc((size_t)ET * 4);
  float* als   = (float*)alloc((size_t)N * 8 * 4);
  float* ald   = (float*)alloc((size_t)N * 8 * 4);
  float* ws3h  = (float*)alloc(6 * 96 * 4);
  float* wd3h  = (float*)alloc(6 * 96 * 4);
  __half* x2h  = (__half*)alloc((size_t)N * 96 * 2);
  // g-region (57.6 MB); x1h and hbuf alias its front (dead before agg3x writes g)
  __half* g    = (__half*)alloc((size_t)N * 576 * 2);
  __half* x1h  = g;                                   // N*112*2 = 11.2 MB
  __half* hbuf = g + (size_t)N * 112;                 // N*112*2 = 11.2 MB (h1 112ch / h2 96ch)

  hipMemsetAsync(cnt, 0, (size_t)N * 4, stream);
  hipMemsetAsync(cnt2, 0, (size_t)N * 4, stream);

  const int B1 = (N + 255) / 256;
  hist_kernel<<<(ET + 255) / 256, 256, 0, stream>>>(ei, E, N, cnt);
  scan1_kernel<<<B1, 256, 0, stream>>>(cnt, N, incl, bsum);
  scan1_kernel<<<1, 256, 0, stream>>>(bsum, B1, bscan, bsum + 256);
  scan3_kernel<<<B1, 256, 0, stream>>>(incl, bscan, N, rowptr);
  scatter_kernel<<<(ET + 255) / 256, 256, 0, stream>>>(ei, E, N, rowptr, cnt2, esorted);
  prep3_kernel<<<6, 96, 0, stream>>>(W3, as3, ad3, ws3h, wd3h);

  // Layer 1: 128 -> 7x16
  gemm_kernel<128, 112, 128, float><<<N / 16, 128, 0, stream>>>(x, W1, hbuf);
  alpha_kernel<7, 16><<<(N * 7 + 255) / 256, 256, 0, stream>>>(hbuf, as1, ad1, als, ald, N);
  agg_kernel<7, 16, 1><<<(N + 3) / 4, 256, 0, stream>>>(hbuf, als, ald, rowptr, esorted, b1, x1h, N);
  // Layer 2: 112 -> 6x16
  gemm_kernel<112, 96, 128, __half><<<N / 16, 128, 0, stream>>>(x1h, W2, hbuf);
  alpha_kernel<6, 16><<<(N * 6 + 255) / 256, 256, 0, stream>>>(hbuf, as2, ad2, als, ald, N);
  agg_kernel<6, 16, 1><<<(N + 3) / 4, 256, 0, stream>>>(hbuf, als, ald, rowptr, esorted, b2, x2h, N);
  // Layer 3 (restructured): logits from x2, aggregate x2 per head, then output GEMM
  alpha3_kernel<<<(N * 6 + 255) / 256, 256, 0, stream>>>(x2h, ws3h, wd3h, als, ald, N);
  agg3x_kernel<<<(N + 3) / 4, 256, 0, stream>>>(x2h, als, ald, rowptr, esorted, g, N);
  gemm3h_kernel<<<N / 16, 256, 0, stream>>>(g, W3, b3, out);
}

// Round 8
// 502.802 us; speedup vs baseline: 1.0844x; 1.0370x over previous
//
#include <hip/hip_runtime.h>
#include <hip/hip_fp16.h>
#include <cstdint>

#define NNODES 50000

__device__ inline void wave_lds_fence() {
  asm volatile("s_waitcnt lgkmcnt(0)" ::: "memory");
  __builtin_amdgcn_wave_barrier();
}

// ---------------- CSR build ----------------
__global__ void hist_kernel(const int* __restrict__ ei, int E, int Nn, int* __restrict__ cnt) {
  int i = blockIdx.x * blockDim.x + threadIdx.x;
  int ET = E + Nn;
  if (i >= ET) return;
  int d = (i < E) ? ei[E + i] : (i - E);
  atomicAdd(&cnt[d], 1);
}

__global__ void scan1_kernel(const int* __restrict__ in, int n, int* __restrict__ incl,
                             int* __restrict__ bsum) {
  __shared__ int sd[256];
  int g = blockIdx.x * 256 + threadIdx.x;
  int v = (g < n) ? in[g] : 0;
  sd[threadIdx.x] = v;
  __syncthreads();
  for (int off = 1; off < 256; off <<= 1) {
    int t = (threadIdx.x >= off) ? sd[threadIdx.x - off] : 0;
    __syncthreads();
    sd[threadIdx.x] += t;
    __syncthreads();
  }
  if (g < n) incl[g] = sd[threadIdx.x];
  if (threadIdx.x == 255) bsum[blockIdx.x] = sd[255];
}

__global__ void scan3_kernel(const int* __restrict__ incl, const int* __restrict__ bscan,
                             int n, int* __restrict__ rowptr) {
  int g = blockIdx.x * 256 + threadIdx.x;
  if (g == 0) rowptr[0] = 0;
  if (g < n) {
    int off = (blockIdx.x > 0) ? bscan[blockIdx.x - 1] : 0;
    rowptr[g + 1] = incl[g] + off;
  }
}

__global__ void scatter_kernel(const int* __restrict__ ei, int E, int Nn,
                               const int* __restrict__ rowptr, int* __restrict__ cnt2,
                               int* __restrict__ esorted) {
  int i = blockIdx.x * blockDim.x + threadIdx.x;
  int ET = E + Nn;
  if (i >= ET) return;
  int s, d;
  if (i < E) { s = ei[i]; d = ei[E + i]; }
  else       { s = i - E; d = i - E; }
  int pos = rowptr[d] + atomicAdd(&cnt2[d], 1);
  esorted[pos] = s;
}

// ---------------- GEMM: Hout[N,HC](fp16) = X[N,FIN] @ W[FIN,HC](fp32) ----------------
template <int FIN, int HC, int BLOCK, typename XT>
__global__ __launch_bounds__(BLOCK) void gemm_kernel(const XT* __restrict__ X,
                                                     const float* __restrict__ W,
                                                     __half* __restrict__ Hout) {
  constexpr int NT = 16;
  constexpr int TM = 4, TN = 4;
  constexpr int CG = HC / TN;
  __shared__ __align__(16) float xs[FIN * NT];  // [k][node]
  const int n0 = blockIdx.x * NT;
  if constexpr (sizeof(XT) == 4) {
    for (int i = threadIdx.x * 4; i < NT * FIN; i += BLOCK * 4) {
      float4 v = *(const float4*)((const float*)X + (size_t)n0 * FIN + i);
      int node = i / FIN, k = i % FIN;
      xs[(k + 0) * NT + node] = v.x;
      xs[(k + 1) * NT + node] = v.y;
      xs[(k + 2) * NT + node] = v.z;
      xs[(k + 3) * NT + node] = v.w;
    }
  } else {
    for (int i = threadIdx.x * 8; i < NT * FIN; i += BLOCK * 8) {
      union { uint4 u; __half2 h2[4]; } raw;
      raw.u = *(const uint4*)((const __half*)X + (size_t)n0 * FIN + i);
      int node = i / FIN, k = i % FIN;  // FIN%8==0 -> same node
#pragma unroll
      for (int j = 0; j < 4; ++j) {
        float2 f = __half22float2(raw.h2[j]);
        xs[(k + 2 * j + 0) * NT + node] = f.x;
        xs[(k + 2 * j + 1) * NT + node] = f.y;
      }
    }
  }
  __syncthreads();
  const int cg = threadIdx.x % CG;
  const int ng = threadIdx.x / CG;
  if (ng >= NT / TM) return;
  const int c0 = cg * TN;
  const int i0 = ng * TM;
  float acc[TM][TN];
#pragma unroll
  for (int i = 0; i < TM; ++i)
#pragma unroll
    for (int j = 0; j < TN; ++j) acc[i][j] = 0.f;
#pragma unroll 4
  for (int k = 0; k < FIN; ++k) {
    const float4 wv = *(const float4*)(W + (size_t)k * HC + c0);
    const float4 xv = *(const float4*)(xs + k * NT + i0);
    acc[0][0] += xv.x * wv.x; acc[0][1] += xv.x * wv.y; acc[0][2] += xv.x * wv.z; acc[0][3] += xv.x * wv.w;
    acc[1][0] += xv.y * wv.x; acc[1][1] += xv.y * wv.y; acc[1][2] += xv.y * wv.z; acc[1][3] += xv.y * wv.w;
    acc[2][0] += xv.z * wv.x; acc[2][1] += xv.z * wv.y; acc[2][2] += xv.z * wv.z; acc[2][3] += xv.z * wv.w;
    acc[3][0] += xv.w * wv.x; acc[3][1] += xv.w * wv.y; acc[3][2] += xv.w * wv.z; acc[3][3] += xv.w * wv.w;
  }
#pragma unroll
  for (int i = 0; i < TM; ++i) {
    union { __half2 h2[2]; uint2 u; } pk;
    pk.h2[0] = __floats2half2_rn(acc[i][0], acc[i][1]);
    pk.h2[1] = __floats2half2_rn(acc[i][2], acc[i][3]);
    *(uint2*)(Hout + (size_t)(n0 + i0 + i) * HC + c0) = pk.u;
  }
}

// ---------------- attention logits (reads fp16 h, writes stride-8 padded) ----------------
template <int H, int C>
__global__ void alpha_kernel(const __half* __restrict__ Hbuf, const float* __restrict__ a_s,
                             const float* __restrict__ a_d, float* __restrict__ als8,
                             float* __restrict__ ald8, int n_nodes) {
  int i = blockIdx.x * blockDim.x + threadIdx.x;
  if (i >= n_nodes * H) return;
  int n = i / H, h = i % H;
  const __half2* hp = (const __half2*)(Hbuf + (size_t)n * H * C + (size_t)h * C);
  float s1 = 0.f, s2 = 0.f;
#pragma unroll
  for (int c = 0; c < C / 2; ++c) {
    float2 f = __half22float2(hp[c]);
    s1 += f.x * a_s[h * C + 2 * c] + f.y * a_s[h * C + 2 * c + 1];
    s2 += f.x * a_d[h * C + 2 * c] + f.y * a_d[h * C + 2 * c + 1];
  }
  als8[n * 8 + h] = s1;
  ald8[n * 8 + h] = s2;
}

// ---------------- segment softmax + aggregate, layers 1-2 (one wave per dst) ----------------
// No max-subtraction: scores are O(+-5); exp() safe in fp32, result identical.
template <int H, int C, int RELU>
__global__ __launch_bounds__(256, 8) void agg_kernel(const __half* __restrict__ Hbuf,
                                                     const float* __restrict__ als8,
                                                     const float* __restrict__ ald8,
                                                     const int* __restrict__ rowptr,
                                                     const int* __restrict__ esrc,
                                                     const float* __restrict__ bias,
                                                     __half* __restrict__ Out, int n_nodes) {
  constexpr int HC = H * C;
  constexpr int PAIRS = HC / 2;  // <= 64
  constexpr int CP2 = C / 2;
  constexpr int UN = 8;          // edge-sweep unroll (MLP)
  constexpr int SW = H | 1;      // odd stride -> conflict-free LDS writes
  const int wave = threadIdx.x >> 6;
  const int lane = threadIdx.x & 63;
  const int n = blockIdx.x * 4 + wave;
  __shared__ float s_w[4][64 * SW];
  __shared__ int s_src[4][64];
  if (n >= n_nodes) return;

  const int e0 = rowptr[n];
  const int e1 = rowptr[n + 1];

  float aldn[H];
#pragma unroll
  for (int h = 0; h < H; ++h) aldn[h] = ald8[n * 8 + h];

  const int pj = lane;
  const int hd = pj / CP2;

  float acc0 = 0.f, acc1 = 0.f;
  float ls[H];
#pragma unroll
  for (int h = 0; h < H; ++h) ls[h] = 0.f;

  for (int base = e0; base < e1; base += 64) {
    const int cnt = (e1 - base < 64) ? (e1 - base) : 64;
    int sreg = 0;
    if (lane < cnt) sreg = esrc[base + lane];
    s_src[wave][lane] = sreg;
    if (lane < cnt) {
      const float4 qa = *(const float4*)(als8 + (size_t)sreg * 8);
      const float4 qb = *(const float4*)(als8 + (size_t)sreg * 8 + 4);
      const float q[8] = {qa.x, qa.y, qa.z, qa.w, qb.x, qb.y, qb.z, qb.w};
#pragma unroll
      for (int h = 0; h < H; ++h) {
        float v = q[h] + aldn[h];
        v = v > 0.f ? v : 0.2f * v;  // leaky_relu 0.2
        float w = __expf(v);
        ls[h] += w;
        s_w[wave][lane * SW + h] = w;
      }
    } else {
#pragma unroll
      for (int h = 0; h < H; ++h) s_w[wave][lane * SW + h] = 0.f;
    }
    wave_lds_fence();
    if (pj < PAIRS) {
      for (int t = 0; t < cnt; t += UN) {
        int so[UN];
#pragma unroll
        for (int k = 0; k < UN; ++k) so[k] = s_src[wave][t + k] * HC;
        __half2 f[UN];
#pragma unroll
        for (int k = 0; k < UN; ++k) f[k] = *(const __half2*)(Hbuf + so[k] + 2 * pj);
#pragma unroll
        for (int k = 0; k < UN; ++k) {
          float w = s_w[wave][(t + k) * SW + hd];
          float2 ff = __half22float2(f[k]);
          acc0 += w * ff.x;
          acc1 += w * ff.y;
        }
      }
    }
    wave_lds_fence();
  }
  // reduce per-head weight sums across the wave (each lane held its own edges' w)
#pragma unroll
  for (int h = 0; h < H; ++h) {
    float v = ls[h];
#pragma unroll
    for (int off = 32; off > 0; off >>= 1) v += __shfl_xor(v, off, 64);
    ls[h] = v;
  }
  if (pj < PAIRS) {
    float inv = 1.f / ls[hd];
    float2 bv = *(const float2*)(bias + 2 * pj);
    float o0 = acc0 * inv + bv.x;
    float o1 = acc1 * inv + bv.y;
    if (RELU) { o0 = fmaxf(o0, 0.f); o1 = fmaxf(o1, 0.f); }
    *(__half2*)(Out + (size_t)n * HC + 2 * pj) = __floats2half2_rn(o0, o1);
  }
}

// ---------------- layer-3 prep: ws3h[h][k] = sum_c W3[k, h*40+c]*a_src3[h,c] ----------------
__global__ void prep3_kernel(const float* __restrict__ W3, const float* __restrict__ as3,
                             const float* __restrict__ ad3, float* __restrict__ ws3h,
                             float* __restrict__ wd3h) {
  int h = blockIdx.x, k = threadIdx.x;  // 6 x 96
  float s1 = 0.f, s2 = 0.f;
  for (int c = 0; c < 40; ++c) {
    float w = W3[k * 240 + h * 40 + c];
    s1 += w * as3[h * 40 + c];
    s2 += w * ad3[h * 40 + c];
  }
  ws3h[h * 96 + k] = s1;
  wd3h[h * 96 + k] = s2;
}

// ---------------- layer-3 logits from x2 directly ----------------
__global__ void alpha3_kernel(const __half* __restrict__ X2h, const float* __restrict__ ws3h,
                              const float* __restrict__ wd3h, float* __restrict__ als8,
                              float* __restrict__ ald8, int n_nodes) {
  int i = blockIdx.x * blockDim.x + threadIdx.x;
  if (i >= n_nodes * 6) return;
  int n = i / 6, h = i % 6;
  const __half2* xp = (const __half2*)(X2h + (size_t)n * 96);
  const float* sp = ws3h + h * 96;
  const float* dp = wd3h + h * 96;
  float s1 = 0.f, s2 = 0.f;
#pragma unroll
  for (int c = 0; c < 48; ++c) {
    float2 f = __half22float2(xp[c]);
    s1 += f.x * sp[2 * c] + f.y * sp[2 * c + 1];
    s2 += f.x * dp[2 * c] + f.y * dp[2 * c + 1];
  }
  als8[n * 8 + h] = s1;
  ald8[n * 8 + h] = s2;
}

// ---------------- layer-3 aggregation in x2-space: g[n,h,:] = sum_e alpha_eh * x2[src_e] ----------------
// (256,4): 128-reg budget -> no scratch spills (the (256,8) 64-reg budget spilled: r5 WRITE 250MB)
__global__ __launch_bounds__(256, 4) void agg3x_kernel(const __half* __restrict__ X2h,
                                                       const float* __restrict__ als8,
                                                       const float* __restrict__ ald8,
                                                       const int* __restrict__ rowptr,
                                                       const int* __restrict__ esrc,
                                                       __half* __restrict__ G, int n_nodes) {
  constexpr int H = 6, CIN = 96, P = 48, UN = 8;
  constexpr int SW = 9;  // odd stride -> conflict-free LDS writes
  const int wave = threadIdx.x >> 6;
  const int lane = threadIdx.x & 63;
  const int n = blockIdx.x * 4 + wave;
  __shared__ float s_w[4][64 * SW];
  __shared__ int s_src[4][64];
  if (n >= n_nodes) return;

  const int e0 = rowptr[n];
  const int e1 = rowptr[n + 1];

  float aldn[H];
#pragma unroll
  for (int h = 0; h < H; ++h) aldn[h] = ald8[n * 8 + h];

  float acc0[H], acc1[H], ls[H];
#pragma unroll
  for (int h = 0; h < H; ++h) { acc0[h] = 0.f; acc1[h] = 0.f; ls[h] = 0.f; }

  for (int base = e0; base < e1; base += 64) {
    const int cnt = (e1 - base < 64) ? (e1 - base) : 64;
    int sreg = 0;
    if (lane < cnt) sreg = esrc[base + lane];
    s_src[wave][lane] = sreg;
    if (lane < cnt) {
      const float4 qa = *(const float4*)(als8 + (size_t)sreg * 8);
      const float2 qb = *(const float2*)(als8 + (size_t)sreg * 8 + 4);
      const float q[6] = {qa.x, qa.y, qa.z, qa.w, qb.x, qb.y};
#pragma unroll
      for (int h = 0; h < H; ++h) {
        float v = q[h] + aldn[h];
        v = v > 0.f ? v : 0.2f * v;
        float w = __expf(v);
        ls[h] += w;
        s_w[wave][lane * SW + h] = w;
      }
    } else {
#pragma unroll
      for (int h = 0; h < H; ++h) s_w[wave][lane * SW + h] = 0.f;
    }
    wave_lds_fence();
    if (lane < P) {
      for (int t = 0; t < cnt; t += UN) {
        int so[UN];
#pragma unroll
        for (int k = 0; k < UN; ++k) so[k] = s_src[wave][t + k] * CIN;
        __half2 f[UN];
#pragma unroll
        for (int k = 0; k < UN; ++k) f[k] = *(const __half2*)(X2h + so[k] + 2 * lane);
#pragma unroll
        for (int k = 0; k < UN; ++k) {
          const float* wp = &s_w[wave][(t + k) * SW];
          float2 ff = __half22float2(f[k]);
#pragma unroll
          for (int h = 0; h < H; ++h) {
            float w = wp[h];  // scalar LDS broadcast
            acc0[h] += w * ff.x;
            acc1[h] += w * ff.y;
          }
        }
      }
    }
    wave_lds_fence();
  }
#pragma unroll
  for (int h = 0; h < H; ++h) {
    float v = ls[h];
#pragma unroll
    for (int off = 32; off > 0; off >>= 1) v += __shfl_xor(v, off, 64);
    ls[h] = 1.f / v;
  }
  if (lane < P) {
#pragma unroll
    for (int h = 0; h < H; ++h) {
      *(__half2*)(G + (size_t)n * 576 + h * 96 + 2 * lane) =
          __floats2half2_rn(acc0[h] * ls[h], acc1[h] * ls[h]);
    }
  }
}

// ---------------- layer-3 output GEMM: out[32 nodes, 240 cols] per block ----------------
// G rows staged row-major, half2-packed (pure uint4 copy: coalesced, conflict-free).
// Reads are wave-broadcasts (<=7 distinct addrs). Block-diagonal: col c uses head c/40's
// 96-slice of G; W3 rows read as coalesced float4 from L2 (575 MB total).
__global__ __launch_bounds__(256, 4) void gemm3h_kernel(const __half* __restrict__ G,
                                                        const float* __restrict__ W3,
                                                        const float* __restrict__ b3,
                                                        float* __restrict__ Out, int n_nodes) {
  constexpr int NT = 32;
  constexpr int RW = 292;          // uints per row: 288 data + 4 pad
  __shared__ uint xs[NT * RW];     // 37376 B
  const int n0 = blockIdx.x * NT;
  const int t = threadIdx.x;
  // stage 32 G rows: 72 uint4 each, fully coalesced (rows beyond n_nodes read pad area)
  for (int i = t; i < NT * 72; i += 256) {
    int node = i / 72, q = (i % 72) * 4;
    uint4 v = *(const uint4*)((const uint*)(G + (size_t)(n0 + node) * 576) + q);
    uint* dst = &xs[node * RW + q];
    dst[0] = v.x; dst[1] = v.y; dst[2] = v.z; dst[3] = v.w;
  }
  __syncthreads();
  const int cg = t % 60;
  const int ng = t / 60;
  if (ng >= 4) return;
  const int c0 = cg * 4;
  const int i0 = ng * 8;            // 8 nodes per thread
  const int kb2 = (c0 / 40) * 48;   // half2-offset of this head's G slice
  float acc[8][4];
#pragma unroll
  for (int i = 0; i < 8; ++i)
#pragma unroll
    for (int j = 0; j < 4; ++j) acc[i][j] = 0.f;
#pragma unroll 2
  for (int kk = 0; kk < 96; kk += 2) {
    const float4 w0 = *(const float4*)(W3 + (size_t)(kk + 0) * 240 + c0);
    const float4 w1 = *(const float4*)(W3 + (size_t)(kk + 1) * 240 + c0);
#pragma unroll
    for (int i = 0; i < 8; ++i) {
      uint u = xs[(i0 + i) * RW + kb2 + (kk >> 1)];
      float2 gf = __half22float2(*(__half2*)&u);
      acc[i][0] += gf.x * w0.x + gf.y * w1.x;
      acc[i][1] += gf.x * w0.y + gf.y * w1.y;
      acc[i][2] += gf.x * w0.z + gf.y * w1.z;
      acc[i][3] += gf.x * w0.w + gf.y * w1.w;
    }
  }
  const float4 bv = *(const float4*)(b3 + c0);
#pragma unroll
  for (int i = 0; i < 8; ++i) {
    int row = n0 + i0 + i;
    if (row < n_nodes) {
      float4 o;
      o.x = acc[i][0] + bv.x; o.y = acc[i][1] + bv.y;
      o.z = acc[i][2] + bv.z; o.w = acc[i][3] + bv.w;
      *(float4*)(Out + (size_t)row * 240 + c0) = o;
    }
  }
}

// ---------------- launch ----------------
extern "C" void kernel_launch(void* const* d_in, const int* in_sizes, int n_in,
                              void* d_out, int out_size, void* d_ws, size_t ws_size,
                              hipStream_t stream) {
  const int N = NNODES;
  const float* x  = (const float*)d_in[0];
  const int* ei   = (const int*)d_in[1];
  const float* W1 = (const float*)d_in[2];
  const float* as1 = (const float*)d_in[3];
  const float* ad1 = (const float*)d_in[4];
  const float* b1  = (const float*)d_in[5];
  const float* W2  = (const float*)d_in[6];
  const float* as2 = (const float*)d_in[7];
  const float* ad2 = (const float*)d_in[8];
  const float* b2  = (const float*)d_in[9];
  const float* W3  = (const float*)d_in[10];
  const float* as3 = (const float*)d_in[11];
  const float* ad3 = (const float*)d_in[12];
  const float* b3  = (const float*)d_in[13];
  float* out = (float*)d_out;
  const int E = in_sizes[1] / 2;
  const int ET = E + N;

  char* ws = (char*)d_ws;
  size_t off = 0;
  auto alloc = [&](size_t bytes) -> char* {
    char* p = ws + off;
    off += (bytes + 255) & ~(size_t)255;
    return p;
  };
  int* cnt     = (int*)alloc((size_t)N * 4);
  int* cnt2    = (int*)alloc((size_t)N * 4);
  int* incl    = (int*)alloc((size_t)N * 4);
  int* bsum    = (int*)alloc(512 * 4);
  int* bscan   = (int*)alloc(256 * 4);
  int* rowptr  = (int*)alloc((size_t)(N + 1) * 4);
  int* esorted = (int*)alloc((size_t)ET * 4);
  float* als   = (float*)alloc((size_t)N * 8 * 4);
  float* ald   = (float*)alloc((size_t)N * 8 * 4);
  float* ws3h  = (float*)alloc(6 * 96 * 4);
  float* wd3h  = (float*)alloc(6 * 96 * 4);
  __half* x2h  = (__half*)alloc((size_t)N * 96 * 2);
  // g-region (57.6 MB + 32-row pad for gemm3h tail); x1h/hbuf alias its front
  __half* g    = (__half*)alloc((size_t)(N + 32) * 576 * 2);
  __half* x1h  = g;                                   // N*112*2 = 11.2 MB
  __half* hbuf = g + (size_t)N * 112;                 // N*112*2 = 11.2 MB (h1 112ch / h2 96ch)

  hipMemsetAsync(cnt, 0, (size_t)N * 4, stream);
  hipMemsetAsync(cnt2, 0, (size_t)N * 4, stream);

  const int B1 = (N + 255) / 256;
  hist_kernel<<<(ET + 255) / 256, 256, 0, stream>>>(ei, E, N, cnt);
  scan1_kernel<<<B1, 256, 0, stream>>>(cnt, N, incl, bsum);
  scan1_kernel<<<1, 256, 0, stream>>>(bsum, B1, bscan, bsum + 256);
  scan3_kernel<<<B1, 256, 0, stream>>>(incl, bscan, N, rowptr);
  scatter_kernel<<<(ET + 255) / 256, 256, 0, stream>>>(ei, E, N, rowptr, cnt2, esorted);
  prep3_kernel<<<6, 96, 0, stream>>>(W3, as3, ad3, ws3h, wd3h);

  // Layer 1: 128 -> 7x16
  gemm_kernel<128, 112, 128, float><<<N / 16, 128, 0, stream>>>(x, W1, hbuf);
  alpha_kernel<7, 16><<<(N * 7 + 255) / 256, 256, 0, stream>>>(hbuf, as1, ad1, als, ald, N);
  agg_kernel<7, 16, 1><<<(N + 3) / 4, 256, 0, stream>>>(hbuf, als, ald, rowptr, esorted, b1, x1h, N);
  // Layer 2: 112 -> 6x16
  gemm_kernel<112, 96, 128, __half><<<N / 16, 128, 0, stream>>>(x1h, W2, hbuf);
  alpha_kernel<6, 16><<<(N * 6 + 255) / 256, 256, 0, stream>>>(hbuf, as2, ad2, als, ald, N);
  agg_kernel<6, 16, 1><<<(N + 3) / 4, 256, 0, stream>>>(hbuf, als, ald, rowptr, esorted, b2, x2h, N);
  // Layer 3 (restructured): logits from x2, aggregate x2 per head, then output GEMM
  alpha3_kernel<<<(N * 6 + 255) / 256, 256, 0, stream>>>(x2h, ws3h, wd3h, als, ald, N);
  agg3x_kernel<<<(N + 3) / 4, 256, 0, stream>>>(x2h, als, ald, rowptr, esorted, g, N);
  gemm3h_kernel<<<(N + 31) / 32, 256, 0, stream>>>(g, W3, b3, out, N);
}